// Round 2
// baseline (858.275 us; speedup 1.0000x reference)
//
#include <hip/hip_runtime.h>

#define NPTS 262144
#define DIM 128
#define KCL 512

constexpr float DECAY = 0.99f;
constexpr float EPSV = 1e-5f;
constexpr float CCOST = 0.25f;

// ---- output layout (floats) ----
#define O_ZQ 0
#define O_LOSS (NPTS * DIM)
#define O_IDX (O_LOSS + 1)
#define O_NECS (O_IDX + NPTS)
#define O_NEMAW (O_NECS + KCL)
#define O_NEMB (O_NEMAW + KCL * DIM)

// ---- workspace layout (4-byte units) ----
#define W_ENORM 0                      // f32[512]
#define W_COUNTS 512                   // u32[512] (zeroed)
#define W_LOSS 1024                    // f32[1]   (zeroed)
#define W_NFLAG 1025                   // u32[1]   (zeroed)
#define W_NFLAG2 1026                  // u32[1]   (zeroed)
#define W_DW 1088                      // f32[65536] (zeroed)
#define W_CS 66624                     // f32[512]
#define W_OFF 67136                    // u32[513]
#define W_CUR 67712                    // u32[512]
#define W_EHI 68224                    // u16[65536] packed fp16-hi, MFMA-frag order
#define W_FLAG2 100992                 // u32[2*FLAG2CAP]
#define FLAG2CAP 4096
#define W_FLAG 109184                  // u32[2*FLAGCAP]
#define FLAGCAP 45056
#define W_IDX 199296                   // i32[N]
#define W_SORTED (W_IDX + NPTS)        // u32[N]

#define MARGIN 0.25f                   // z-hi x e-hi pass: dist err std ~9e-3 -> 28 sigma
#define MARGIN2 0.005f                 // fp32-dot tier-1: err ~2e-5 -> 250x cover
#define SEG 64
#define RB 16                          // recheck1 points per batch

using v8h = __attribute__((ext_vector_type(8))) _Float16;
using v4f = __attribute__((ext_vector_type(4))) float;

// One-time: embedding fp16-hi into MFMA B-fragment order + ||e||^2.
// packed[((gg*4+ks)*64 + lane)*8 + j] = e[gg*16 + (lane&15)][ks*32 + (lane>>4)*8 + j]
__global__ void k_prep(const float* __restrict__ emb,
                       unsigned short* __restrict__ ehi,
                       float* __restrict__ wsf) {
    __shared__ float part[4][16];
    const int t = threadIdx.x;          // 256
    const int g = blockIdx.x;           // 32 blocks: one 16-cluster group each
    const int lane = t & 63, ks = t >> 6;
    const int col = lane & 15, quad = lane >> 4;
    const float* src = emb + (size_t)(g * 16 + col) * DIM + ks * 32 + quad * 8;
    float4 a = *(const float4*)src;
    float4 b = *(const float4*)(src + 4);
    float f[8] = {a.x, a.y, a.z, a.w, b.x, b.y, b.z, b.w};
    union { unsigned short s[8]; int4 v; } uh;
    float s2 = 0.0f;
#pragma unroll
    for (int j = 0; j < 8; j++) {
        _Float16 h = (_Float16)f[j];
        uh.s[j] = __builtin_bit_cast(unsigned short, h);
        s2 += f[j] * f[j];
    }
    *(int4*)&ehi[((size_t)g * 256 + t) * 8] = uh.v;
    s2 += __shfl_xor(s2, 16);
    s2 += __shfl_xor(s2, 32);
    if (quad == 0) part[ks][col] = s2;
    __syncthreads();
    if (t < 16)
        wsf[W_ENORM + g * 16 + t] = part[0][t] + part[1][t] + part[2][t] + part[3][t];
}

// Distance GEMM: 128 points x 512 clusters per block, z-hi only (1 MFMA/cell).
// B streamed in 64-cluster chunks, double-buffered LDS (2x16 KB), T14 split:
// next chunk's loads issued before current chunk's compute.
__global__ __launch_bounds__(256, 4) void k_main(
    const float* __restrict__ z, const float* __restrict__ emb,
    const unsigned short* __restrict__ ehi,
    float* __restrict__ out, float* __restrict__ wsf,
    unsigned* __restrict__ wsu, int* __restrict__ wsi) {
    __shared__ short sbuf[2][8192];     // 2 x 16 KB chunk buffers (frag order)
    __shared__ float sen[KCL];
    __shared__ int   ishs[128];

    const int t = threadIdx.x;          // 256
    const int blk = blockIdx.x;         // 2048
    const int w = t >> 6;               // 0..3
    const int lane = t & 63;
    const int col = lane & 15;
    const int quad = lane >> 4;

    sen[t] = wsf[W_ENORM + t];
    sen[t + 256] = wsf[W_ENORM + t + 256];

    // ---- prologue: stage chunk 0 ----
    int4 stg[4];
    {
        const int4* src = (const int4*)ehi;
#pragma unroll
        for (int i = 0; i < 4; i++) stg[i] = src[t + 256 * i];
    }

    // ---- A fragments: z hi in registers + exact ||z||^2 ----
    v8h ah[2][4];
    float zn[2];
#pragma unroll
    for (int mt = 0; mt < 2; mt++) {
        zn[mt] = 0.0f;
        const float* zr = z + (size_t)(blk * 128 + w * 32 + mt * 16 + col) * DIM;
#pragma unroll
        for (int ks = 0; ks < 4; ks++) {
            const float* p = zr + ks * 32 + quad * 8;
            float4 a = *(const float4*)p;
            float4 b = *(const float4*)(p + 4);
            float f[8] = {a.x, a.y, a.z, a.w, b.x, b.y, b.z, b.w};
#pragma unroll
            for (int j = 0; j < 8; j++) {
                ah[mt][ks][j] = (_Float16)f[j];
                zn[mt] += f[j] * f[j];
            }
        }
        zn[mt] += __shfl_xor(zn[mt], 16);
        zn[mt] += __shfl_xor(zn[mt], 32);
    }

#pragma unroll
    for (int i = 0; i < 4; i++) ((int4*)sbuf[0])[t + 256 * i] = stg[i];
    __syncthreads();

    float rv1[8], rv2[8];
    int ri1[8];
#pragma unroll
    for (int s = 0; s < 8; s++) { rv1[s] = 3.4e38f; rv2[s] = 3.4e38f; ri1[s] = 0; }

    for (int kt = 0; kt < 8; kt++) {
        const short* bcur = sbuf[kt & 1];
        // T14: issue next chunk's global loads (fly under compute)
        if (kt < 7) {
            const int4* src = (const int4*)ehi + (kt + 1) * 1024;
#pragma unroll
            for (int i = 0; i < 4; i++) stg[i] = src[t + 256 * i];
        }
#pragma unroll
        for (int g = 0; g < 4; g++) {
            v8h bh[4];
#pragma unroll
            for (int ks = 0; ks < 4; ks++)
                bh[ks] = *(const v8h*)&bcur[((g * 4 + ks) * 64 + lane) * 8];
            v4f acc0 = {0.f, 0.f, 0.f, 0.f}, acc1 = {0.f, 0.f, 0.f, 0.f};
#pragma unroll
            for (int ks = 0; ks < 4; ks++) {
                acc0 = __builtin_amdgcn_mfma_f32_16x16x32_f16(ah[0][ks], bh[ks], acc0, 0, 0, 0);
                acc1 = __builtin_amdgcn_mfma_f32_16x16x32_f16(ah[1][ks], bh[ks], acc1, 0, 0, 0);
            }
            const int kbase = (kt * 4 + g) * 16 + col;
            const float en = sen[kbase];
#pragma unroll
            for (int mt = 0; mt < 2; mt++)
#pragma unroll
                for (int r = 0; r < 4; r++) {
                    int s = mt * 4 + r;
                    float dist = fmaf(-2.0f, (mt ? acc1[r] : acc0[r]), en);
                    bool better = dist < rv1[s];
                    rv2[s] = fminf(fmaxf(dist, rv1[s]), rv2[s]);   // med3
                    rv1[s] = better ? dist : rv1[s];
                    ri1[s] = better ? kbase : ri1[s];
                }
        }
        if (kt < 7) {
            short* bnxt = sbuf[(kt & 1) ^ 1];
#pragma unroll
            for (int i = 0; i < 4; i++) ((int4*)bnxt)[t + 256 * i] = stg[i];
        }
        __syncthreads();
    }

    // ---- butterfly merge across the 16 cols (wave covers all 512 clusters) ----
#pragma unroll
    for (int m = 1; m < 16; m <<= 1) {
#pragma unroll
        for (int s = 0; s < 8; s++) {
            float c1 = __shfl_xor(rv1[s], m);
            int ci1 = __shfl_xor(ri1[s], m);
            float c2 = __shfl_xor(rv2[s], m);
            if (c1 < rv1[s] || (c1 == rv1[s] && ci1 < ri1[s])) {
                rv2[s] = fminf(rv1[s], c2);
                rv1[s] = c1; ri1[s] = ci1;
            } else {
                rv2[s] = fminf(rv2[s], c1);
            }
        }
    }

    float znp[8];
#pragma unroll
    for (int s = 0; s < 8; s++) znp[s] = __shfl(zn[s >> 2], quad * 4 + (s & 3));

    float lossacc = 0.0f;
    if (col == 0) {
#pragma unroll
        for (int s = 0; s < 8; s++) {
            int p = w * 32 + (s >> 2) * 16 + quad * 4 + (s & 3);
            int gp = blk * 128 + p;
            float v1 = rv1[s]; int i1 = ri1[s];
            float fd = v1 + znp[s];
            out[O_IDX + gp] = (float)i1;
            wsi[W_IDX + gp] = i1;
            ishs[p] = i1;
            atomicAdd(&wsu[W_COUNTS + i1], 1u);
            lossacc += fd;
            if (rv2[s] - v1 < MARGIN) {
                unsigned pos = atomicAdd(&wsu[W_NFLAG], 1u);
                if (pos < FLAGCAP) {
                    wsu[W_FLAG + 2 * pos] = (unsigned)gp;
                    wsu[W_FLAG + 2 * pos + 1] = __float_as_uint(fd);
                }
            }
        }
    }
    for (int o = 32; o > 0; o >>= 1) lossacc += __shfl_down(lossacc, o);
    if (lane == 0) atomicAdd(&wsf[W_LOSS], lossacc);

    __syncthreads();
    // ---- z_q gather: 128 rows x 128 f32 ----
    float* outz = out + (size_t)blk * 128 * DIM;
#pragma unroll
    for (int i = 0; i < 16; i++) {
        int f4 = t + 256 * i;            // 0..4095
        int p = f4 >> 5, dq = f4 & 31;
        int ci = ishs[p];
        float4 v = *(const float4*)(emb + (size_t)ci * DIM + 4 * dq);
        ((float4*)outz)[f4] = v;
    }
}

// Tier-1 recheck: batched fp32 exact-z dot full scan. 16 points/block share one
// emb stream; thread owns 2 clusters x 16 points.
__global__ __launch_bounds__(256) void k_recheck1(
    const float* __restrict__ z, const float* __restrict__ emb,
    float* __restrict__ out, float* __restrict__ wsf,
    unsigned* __restrict__ wsu, int* __restrict__ wsi) {
    __shared__ float zs[RB][DIM];        // 8 KB
    __shared__ float zns[RB];
    __shared__ unsigned sgp[RB];
    __shared__ float sfd[RB];
    __shared__ float r1[RB][257];        // padded: cross-thread reduce arrays
    __shared__ float r2[RB][257];
    __shared__ int   rix[RB][257];
    const int t = threadIdx.x;
    unsigned nf = wsu[W_NFLAG];
    if (nf > FLAGCAP) nf = FLAGCAP;
    unsigned nb = (nf + RB - 1) / RB;
    for (unsigned b = blockIdx.x; b < nb; b += gridDim.x) {
        __syncthreads();
        if (t < RB) {
            unsigned fi = b * RB + t;
            if (fi < nf) {
                sgp[t] = wsu[W_FLAG + 2 * fi];
                sfd[t] = __uint_as_float(wsu[W_FLAG + 2 * fi + 1]);
            } else { sgp[t] = 0u; sfd[t] = 0.0f; }
        }
        __syncthreads();
        // stage 16 z-rows (16 threads per row, 8 floats each)
        {
            int p = t >> 4, j = t & 15;
            const float4* src = (const float4*)(z + (size_t)sgp[p] * DIM);
            *(float4*)&zs[p][j * 8] = src[j * 2];
            *(float4*)&zs[p][j * 8 + 4] = src[j * 2 + 1];
        }
        __syncthreads();
        if (t < RB) {
            float s = 0.0f;
            for (int d = 0; d < DIM; d += 4) {
                float4 v = *(const float4*)&zs[t][d];
                s += v.x * v.x + v.y * v.y + v.z * v.z + v.w * v.w;
            }
            zns[t] = s;
        }
        // dots: clusters c0=2t, c1=2t+1 vs all 16 points
        float acc0[RB], acc1[RB];
#pragma unroll
        for (int p = 0; p < RB; p++) { acc0[p] = 0.0f; acc1[p] = 0.0f; }
        const float4* e0 = (const float4*)(emb + (size_t)(2 * t) * DIM);
        const float4* e1 = (const float4*)(emb + (size_t)(2 * t + 1) * DIM);
#pragma unroll 2
        for (int ch = 0; ch < 32; ch++) {
            float4 ea = e0[ch], eb = e1[ch];
#pragma unroll
            for (int p = 0; p < RB; p++) {
                float4 zv = *(const float4*)&zs[p][ch * 4];   // LDS broadcast
                acc0[p] = fmaf(zv.x, ea.x, fmaf(zv.y, ea.y, fmaf(zv.z, ea.z, fmaf(zv.w, ea.w, acc0[p]))));
                acc1[p] = fmaf(zv.x, eb.x, fmaf(zv.y, eb.y, fmaf(zv.z, eb.z, fmaf(zv.w, eb.w, acc1[p]))));
            }
        }
        float en0 = wsf[W_ENORM + 2 * t];
        float en1 = wsf[W_ENORM + 2 * t + 1];
#pragma unroll
        for (int p = 0; p < RB; p++) {
            float d0 = fmaf(-2.0f, acc0[p], en0);
            float d1 = fmaf(-2.0f, acc1[p], en1);
            float v1 = d0, v2 = d1; int i1 = 2 * t;
            if (d1 < d0) { v1 = d1; i1 = 2 * t + 1; v2 = d0; }
            r1[p][t] = v1; rix[p][t] = i1; r2[p][t] = v2;
        }
        __syncthreads();
        // per-point reduce: 16 threads/point, then in-wave butterfly
        {
            int p = t >> 4, j = t & 15;
            float v1 = 3.4e38f, v2 = 3.4e38f; int i1 = 0x7fffffff;
#pragma unroll
            for (int k = 0; k < 16; k++) {
                int idx = j + 16 * k;
                float c1 = r1[p][idx]; int ci = rix[p][idx]; float c2 = r2[p][idx];
                if (c1 < v1 || (c1 == v1 && ci < i1)) { v2 = fminf(v1, c2); v1 = c1; i1 = ci; }
                else v2 = fminf(v2, c1);
            }
#pragma unroll
            for (int m = 1; m < 16; m <<= 1) {
                float c1 = __shfl_xor(v1, m);
                int ci = __shfl_xor(i1, m);
                float c2 = __shfl_xor(v2, m);
                if (c1 < v1 || (c1 == v1 && ci < i1)) { v2 = fminf(v1, c2); v1 = c1; i1 = ci; }
                else v2 = fminf(v2, c1);
            }
            bool valid = (b * RB + (unsigned)p < nf);
            unsigned gp = sgp[p];
            int chg = 0;
            if (j == 0 && valid) {
                if (v2 - v1 < MARGIN2) {
                    unsigned pos = atomicAdd(&wsu[W_NFLAG2], 1u);
                    if (pos < FLAG2CAP) {
                        wsu[W_FLAG2 + 2 * pos] = gp;
                        wsu[W_FLAG2 + 2 * pos + 1] = __float_as_uint(sfd[p]);
                    }
                } else {
                    float d = v1 + zns[p];
                    atomicAdd(&wsf[W_LOSS], d - sfd[p]);
                    int iold = wsi[W_IDX + gp];
                    if (i1 != iold) {
                        chg = 1;
                        wsi[W_IDX + gp] = i1;
                        out[O_IDX + gp] = (float)i1;
                        atomicAdd(&wsu[W_COUNTS + iold], (unsigned)-1);
                        atomicAdd(&wsu[W_COUNTS + i1], 1u);
                    }
                }
            }
            chg = __shfl(chg, (t & 63) & ~15);
            if (chg) {   // i1, gp identical across the 16-lane group
                int dd = j * 8;
                *(float4*)&out[(size_t)gp * DIM + dd] =
                    *(const float4*)&emb[(size_t)i1 * DIM + dd];
                *(float4*)&out[(size_t)gp * DIM + dd + 4] =
                    *(const float4*)&emb[(size_t)i1 * DIM + dd + 4];
            }
        }
    }
}

// Tier-2: fp64 full-scan for ultra-near ties (expected ~hundreds)
__global__ __launch_bounds__(256) void k_recheck2(
    const float* __restrict__ z, const float* __restrict__ emb,
    float* __restrict__ out, float* __restrict__ wsf,
    unsigned* __restrict__ wsu, int* __restrict__ wsi) {
    __shared__ float zrow[DIM];
    __shared__ double sd[256];
    __shared__ int si[256];
    __shared__ int schg, snew;
    const int t = threadIdx.x;
    unsigned nf = wsu[W_NFLAG2];
    if (nf > FLAG2CAP) nf = FLAG2CAP;
    for (unsigned fi = blockIdx.x; fi < nf; fi += gridDim.x) {
        unsigned gp = wsu[W_FLAG2 + 2 * fi];
        float fd_prov = __uint_as_float(wsu[W_FLAG2 + 2 * fi + 1]);
        __syncthreads();
        if (t < DIM) zrow[t] = z[(size_t)gp * DIM + t];
        __syncthreads();
        double best = 1e300; int bi = 0;
        for (int c = t; c < KCL; c += 256) {
            const float* er = emb + (size_t)c * DIM;
            double d = 0.0;
            for (int dd = 0; dd < DIM; dd++) {
                double df = (double)zrow[dd] - (double)er[dd];
                d += df * df;
            }
            if (d < best) { best = d; bi = c; }
        }
        sd[t] = best; si[t] = bi;
        __syncthreads();
        for (int o = 128; o > 0; o >>= 1) {
            if (t < o) {
                if (sd[t + o] < sd[t] || (sd[t + o] == sd[t] && si[t + o] < si[t])) {
                    sd[t] = sd[t + o]; si[t] = si[t + o];
                }
            }
            __syncthreads();
        }
        if (t == 0) {
            int inew = si[0];
            int iold = wsi[W_IDX + gp];
            snew = inew;
            schg = (inew != iold);
            atomicAdd(&wsf[W_LOSS], (float)sd[0] - fd_prov);
            if (inew != iold) {
                wsi[W_IDX + gp] = inew;
                out[O_IDX + gp] = (float)inew;
                atomicAdd(&wsu[W_COUNTS + iold], (unsigned)-1);
                atomicAdd(&wsu[W_COUNTS + inew], 1u);
            }
        }
        __syncthreads();
        if (schg && t < DIM) out[(size_t)gp * DIM + t] = emb[(size_t)snew * DIM + t];
        __syncthreads();
    }
}

__global__ void k_finalize(const float* __restrict__ ema_cs, float* __restrict__ out,
                           float* __restrict__ wsf, unsigned* __restrict__ wsu) {
    __shared__ float s[KCL];
    __shared__ unsigned sc[KCL];
    int t = threadIdx.x;  // 512 threads
    unsigned c = wsu[W_COUNTS + t];
    float necs = ema_cs[t] * DECAY + (1.0f - DECAY) * (float)c;
    out[O_NECS + t] = necs;
    s[t] = necs;
    __syncthreads();
    for (int o = 256; o > 0; o >>= 1) {
        if (t < o) s[t] += s[t + o];
        __syncthreads();
    }
    float n = s[0];
    float cs = (necs + EPSV) / (n + (float)KCL * EPSV) * n;
    wsf[W_CS + t] = cs;
    sc[t] = c;
    __syncthreads();
    for (int o = 1; o < KCL; o <<= 1) {
        unsigned v = (t >= o) ? sc[t - o] : 0u;
        __syncthreads();
        sc[t] += v;
        __syncthreads();
    }
    unsigned excl = sc[t] - c;
    wsu[W_OFF + t] = excl;
    wsu[W_CUR + t] = excl;
    if (t == 0) {
        out[O_LOSS] = CCOST * wsf[W_LOSS] / (float)((size_t)NPTS * DIM);
        wsu[W_OFF + KCL] = NPTS;
    }
}

__global__ void k_scatter(unsigned* __restrict__ wsu, const int* __restrict__ wsi) {
    int p = blockIdx.x * blockDim.x + threadIdx.x;
    int k = wsi[W_IDX + p];
    unsigned pos = atomicAdd(&wsu[W_CUR + k], 1u);
    wsu[W_SORTED + pos] = (unsigned)p;
}

__global__ __launch_bounds__(256) void k_dwseg(
    const float* __restrict__ z, float* __restrict__ wsf,
    const unsigned* __restrict__ wsu) {
    __shared__ unsigned soff[KCL + 1];
    __shared__ unsigned sidx[SEG];
    const int t = threadIdx.x;
    for (int i = t; i < KCL + 1; i += 256) soff[i] = wsu[W_OFF + i];
    const int base = blockIdx.x * SEG;
    if (t < SEG) sidx[t] = wsu[W_SORTED + base + t];
    __syncthreads();

    const int r = t >> 7;
    const int d = t & 127;
    const int pos0 = base + r;
    int lo = 0, hi = KCL;
    while (lo < hi) {
        int mid = (lo + hi + 1) >> 1;
        if (soff[mid] <= (unsigned)pos0) lo = mid; else hi = mid - 1;
    }
    int curk = lo;
    float acc = 0.0f;
#pragma unroll 4
    for (int j = 0; j < SEG / 2; j++) {
        int pos = pos0 + 2 * j;
        unsigned p = sidx[pos - base];
        while ((unsigned)pos >= soff[curk + 1]) {
            if (acc != 0.0f) atomicAdd(&wsf[W_DW + curk * DIM + d], acc);
            acc = 0.0f;
            curk++;
        }
        acc += z[(size_t)p * DIM + d];
    }
    atomicAdd(&wsf[W_DW + curk * DIM + d], acc);
}

__global__ void k_emb(const float* __restrict__ ema_w, float* __restrict__ out,
                      const float* __restrict__ wsf) {
    int i = blockIdx.x * 256 + threadIdx.x;
    int k = i >> 7;
    float dw = wsf[W_DW + i];
    float nw = ema_w[i] * DECAY + (1.0f - DECAY) * dw;
    out[O_NEMAW + i] = nw;
    out[O_NEMB + i] = nw / wsf[W_CS + k];
}

extern "C" void kernel_launch(void* const* d_in, const int* in_sizes, int n_in,
                              void* d_out, int out_size, void* d_ws, size_t ws_size,
                              hipStream_t stream) {
    const float* z = (const float*)d_in[0];
    const float* emb = (const float*)d_in[1];
    const float* ema_cs = (const float*)d_in[2];
    const float* ema_w = (const float*)d_in[3];
    float* out = (float*)d_out;
    float* wsf = (float*)d_ws;
    unsigned* wsu = (unsigned*)d_ws;
    int* wsi = (int*)d_ws;
    unsigned short* ehi = (unsigned short*)(wsu + W_EHI);

    // zero counts + loss + nflag + nflag2 + dw (contiguous region)
    hipMemsetAsync((char*)d_ws + (size_t)W_COUNTS * 4, 0,
                   (size_t)(W_DW + KCL * DIM - W_COUNTS) * 4, stream);

    k_prep<<<32, 256, 0, stream>>>(emb, ehi, wsf);
    k_main<<<NPTS / 128, 256, 0, stream>>>(z, emb, ehi, out, wsf, wsu, wsi);
    k_recheck1<<<512, 256, 0, stream>>>(z, emb, out, wsf, wsu, wsi);
    k_recheck2<<<256, 256, 0, stream>>>(z, emb, out, wsf, wsu, wsi);
    k_finalize<<<1, KCL, 0, stream>>>(ema_cs, out, wsf, wsu);
    k_scatter<<<NPTS / 256, 256, 0, stream>>>(wsu, wsi);
    k_dwseg<<<NPTS / SEG, 256, 0, stream>>>(z, wsf, wsu);
    k_emb<<<KCL * DIM / 256, 256, 0, stream>>>(ema_w, out, wsf);
}

// Round 3
// 828.135 us; speedup vs baseline: 1.0364x; 1.0364x over previous
//
#include <hip/hip_runtime.h>

#define NPTS 262144
#define DIM 128
#define KCL 512

constexpr float DECAY = 0.99f;
constexpr float EPSV = 1e-5f;
constexpr float CCOST = 0.25f;

// ---- output layout (floats) ----
#define O_ZQ 0
#define O_LOSS (NPTS * DIM)
#define O_IDX (O_LOSS + 1)
#define O_NECS (O_IDX + NPTS)
#define O_NEMAW (O_NECS + KCL)
#define O_NEMB (O_NEMAW + KCL * DIM)

// ---- workspace layout (4-byte units) ----
#define W_ENORM 0                      // f32[512]
#define W_COUNTS 512                   // u32[512] (zeroed)
#define W_LOSS 1024                    // f32[1]   (zeroed)
#define W_NFLAG 1025                   // u32[1]   (zeroed)
#define W_NFLAG2 1026                  // u32[1]   (zeroed)
#define W_DW 1088                      // f32[65536] (zeroed)
#define W_CS 66624                     // f32[512]
#define W_OFF 67136                    // u32[513]
#define W_CUR 67712                    // u32[512]
#define W_EHI 68224                    // u16[65536] packed fp16-hi, MFMA-frag order
#define W_FLAG2 100992                 // u32[2*FLAG2CAP]
#define FLAG2CAP 4096
#define W_FLAG 109184                  // u32[2*FLAGCAP]
#define FLAGCAP 45056
#define W_IDX 199296                   // i32[N]
#define W_SORTED (W_IDX + NPTS)        // u32[N]

#define MARGIN 0.25f                   // z-hi x e-hi pass: dist err std ~9e-3 -> 28 sigma
#define MARGIN2 0.005f                 // fp32-dot tier-1: err ~2e-5 -> 250x cover
#define SEG 64
#define RB 16                          // recheck1 points per batch

using v8h = __attribute__((ext_vector_type(8))) _Float16;
using v4f = __attribute__((ext_vector_type(4))) float;

// One-time: embedding fp16-hi into MFMA B-fragment order + ||e||^2.
// packed[((gg*4+ks)*64 + lane)*8 + j] = e[gg*16 + (lane&15)][ks*32 + (lane>>4)*8 + j]
__global__ void k_prep(const float* __restrict__ emb,
                       unsigned short* __restrict__ ehi,
                       float* __restrict__ wsf) {
    __shared__ float part[4][16];
    const int t = threadIdx.x;          // 256
    const int g = blockIdx.x;           // 32 blocks: one 16-cluster group each
    const int lane = t & 63, ks = t >> 6;
    const int col = lane & 15, quad = lane >> 4;
    const float* src = emb + (size_t)(g * 16 + col) * DIM + ks * 32 + quad * 8;
    float4 a = *(const float4*)src;
    float4 b = *(const float4*)(src + 4);
    float f[8] = {a.x, a.y, a.z, a.w, b.x, b.y, b.z, b.w};
    union { unsigned short s[8]; int4 v; } uh;
    float s2 = 0.0f;
#pragma unroll
    for (int j = 0; j < 8; j++) {
        _Float16 h = (_Float16)f[j];
        uh.s[j] = __builtin_bit_cast(unsigned short, h);
        s2 += f[j] * f[j];
    }
    *(int4*)&ehi[((size_t)g * 256 + t) * 8] = uh.v;
    s2 += __shfl_xor(s2, 16);
    s2 += __shfl_xor(s2, 32);
    if (quad == 0) part[ks][col] = s2;
    __syncthreads();
    if (t < 16)
        wsf[W_ENORM + g * 16 + t] = part[0][t] + part[1][t] + part[2][t] + part[3][t];
}

// Distance GEMM: 128 points x 512 clusters per block, z-hi only (1 MFMA/cell).
// B streamed in 64-cluster chunks, double-buffered LDS (2x16 KB), staged via
// global_load_lds (direct-to-LDS DMA, no VGPR round trip -> no spill).
__global__ __launch_bounds__(256, 4) void k_main(
    const float* __restrict__ z, const float* __restrict__ emb,
    const unsigned short* __restrict__ ehi,
    float* __restrict__ out, float* __restrict__ wsf,
    unsigned* __restrict__ wsu, int* __restrict__ wsi) {
    __shared__ short sbuf[2][8192];     // 2 x 16 KB chunk buffers (frag order)
    __shared__ float sen[KCL];
    __shared__ int   ishs[128];

    const int t = threadIdx.x;          // 256
    const int blk = blockIdx.x;         // 2048
    const int w = t >> 6;               // 0..3
    const int lane = t & 63;
    const int col = lane & 15;
    const int quad = lane >> 4;

    sen[t] = wsf[W_ENORM + t];
    sen[t + 256] = wsf[W_ENORM + t + 256];

    // ---- prologue: stage chunk 0 into buf 0 (async DMA; wave w covers 4 KB) ----
    {
        const char* g = (const char*)ehi + (size_t)w * 4096 + (size_t)lane * 16;
        char* l = (char*)&sbuf[0][0] + w * 4096;
#pragma unroll
        for (int i = 0; i < 4; i++)
            __builtin_amdgcn_global_load_lds(
                (const __attribute__((address_space(1))) void*)(g + i * 1024),
                (__attribute__((address_space(3))) void*)(l + i * 1024), 16, 0, 0);
    }

    // ---- A fragments: z hi in registers + exact ||z||^2 (overlaps DMA) ----
    v8h ah[2][4];
    float zn[2];
#pragma unroll
    for (int mt = 0; mt < 2; mt++) {
        zn[mt] = 0.0f;
        const float* zr = z + (size_t)(blk * 128 + w * 32 + mt * 16 + col) * DIM;
#pragma unroll
        for (int ks = 0; ks < 4; ks++) {
            const float* p = zr + ks * 32 + quad * 8;
            float4 a = *(const float4*)p;
            float4 b = *(const float4*)(p + 4);
            float f[8] = {a.x, a.y, a.z, a.w, b.x, b.y, b.z, b.w};
#pragma unroll
            for (int j = 0; j < 8; j++) {
                ah[mt][ks][j] = (_Float16)f[j];
                zn[mt] += f[j] * f[j];
            }
        }
        zn[mt] += __shfl_xor(zn[mt], 16);
        zn[mt] += __shfl_xor(zn[mt], 32);
    }

    __syncthreads();    // drains vmcnt -> chunk 0 resident for all waves

    float rv1[8], rv2[8];
    int ri1[8];
#pragma unroll
    for (int s = 0; s < 8; s++) { rv1[s] = 3.4e38f; rv2[s] = 3.4e38f; ri1[s] = 0; }

    for (int kt = 0; kt < 8; kt++) {
        const short* bcur = sbuf[kt & 1];
        // async-stage next chunk into the other buffer (flies under compute)
        if (kt < 7) {
            const char* g = (const char*)ehi + (size_t)(kt + 1) * 16384
                            + (size_t)w * 4096 + (size_t)lane * 16;
            char* l = (char*)&sbuf[(kt & 1) ^ 1][0] + w * 4096;
#pragma unroll
            for (int i = 0; i < 4; i++)
                __builtin_amdgcn_global_load_lds(
                    (const __attribute__((address_space(1))) void*)(g + i * 1024),
                    (__attribute__((address_space(3))) void*)(l + i * 1024), 16, 0, 0);
        }
#pragma unroll
        for (int g = 0; g < 4; g++) {
            v8h bh[4];
#pragma unroll
            for (int ks = 0; ks < 4; ks++)
                bh[ks] = *(const v8h*)&bcur[((g * 4 + ks) * 64 + lane) * 8];
            v4f acc0 = {0.f, 0.f, 0.f, 0.f}, acc1 = {0.f, 0.f, 0.f, 0.f};
#pragma unroll
            for (int ks = 0; ks < 4; ks++) {
                acc0 = __builtin_amdgcn_mfma_f32_16x16x32_f16(ah[0][ks], bh[ks], acc0, 0, 0, 0);
                acc1 = __builtin_amdgcn_mfma_f32_16x16x32_f16(ah[1][ks], bh[ks], acc1, 0, 0, 0);
            }
            const int kbase = (kt * 4 + g) * 16 + col;
            const float en = sen[kbase];
#pragma unroll
            for (int mt = 0; mt < 2; mt++)
#pragma unroll
                for (int r = 0; r < 4; r++) {
                    int s = mt * 4 + r;
                    float dist = fmaf(-2.0f, (mt ? acc1[r] : acc0[r]), en);
                    bool better = dist < rv1[s];
                    rv2[s] = fminf(fmaxf(dist, rv1[s]), rv2[s]);   // med3
                    rv1[s] = better ? dist : rv1[s];
                    ri1[s] = better ? kbase : ri1[s];
                }
        }
        __syncthreads();   // compiler drains vmcnt before barrier -> next buf ready
    }

    // ---- butterfly merge across the 16 cols (wave covers all 512 clusters) ----
#pragma unroll
    for (int m = 1; m < 16; m <<= 1) {
#pragma unroll
        for (int s = 0; s < 8; s++) {
            float c1 = __shfl_xor(rv1[s], m);
            int ci1 = __shfl_xor(ri1[s], m);
            float c2 = __shfl_xor(rv2[s], m);
            if (c1 < rv1[s] || (c1 == rv1[s] && ci1 < ri1[s])) {
                rv2[s] = fminf(rv1[s], c2);
                rv1[s] = c1; ri1[s] = ci1;
            } else {
                rv2[s] = fminf(rv2[s], c1);
            }
        }
    }

    float znp[8];
#pragma unroll
    for (int s = 0; s < 8; s++) znp[s] = __shfl(zn[s >> 2], quad * 4 + (s & 3));

    float lossacc = 0.0f;
    if (col == 0) {
#pragma unroll
        for (int s = 0; s < 8; s++) {
            int p = w * 32 + (s >> 2) * 16 + quad * 4 + (s & 3);
            int gp = blk * 128 + p;
            float v1 = rv1[s]; int i1 = ri1[s];
            float fd = v1 + znp[s];
            out[O_IDX + gp] = (float)i1;
            wsi[W_IDX + gp] = i1;
            ishs[p] = i1;
            atomicAdd(&wsu[W_COUNTS + i1], 1u);
            lossacc += fd;
            if (rv2[s] - v1 < MARGIN) {
                unsigned pos = atomicAdd(&wsu[W_NFLAG], 1u);
                if (pos < FLAGCAP) {
                    wsu[W_FLAG + 2 * pos] = (unsigned)gp;
                    wsu[W_FLAG + 2 * pos + 1] = __float_as_uint(fd);
                }
            }
        }
    }
    for (int o = 32; o > 0; o >>= 1) lossacc += __shfl_down(lossacc, o);
    if (lane == 0) atomicAdd(&wsf[W_LOSS], lossacc);

    __syncthreads();
    // ---- z_q gather: 128 rows x 128 f32 ----
    float* outz = out + (size_t)blk * 128 * DIM;
#pragma unroll
    for (int i = 0; i < 16; i++) {
        int f4 = t + 256 * i;            // 0..4095
        int p = f4 >> 5, dq = f4 & 31;
        int ci = ishs[p];
        float4 v = *(const float4*)(emb + (size_t)ci * DIM + 4 * dq);
        ((float4*)outz)[f4] = v;
    }
}

// Tier-1 recheck: batched fp32 exact-z dot full scan. 16 points/block share one
// emb stream; thread owns 2 clusters x 16 points.
__global__ __launch_bounds__(256) void k_recheck1(
    const float* __restrict__ z, const float* __restrict__ emb,
    float* __restrict__ out, float* __restrict__ wsf,
    unsigned* __restrict__ wsu, int* __restrict__ wsi) {
    __shared__ float zs[RB][DIM];        // 8 KB
    __shared__ float zns[RB];
    __shared__ unsigned sgp[RB];
    __shared__ float sfd[RB];
    __shared__ float r1[RB][257];        // padded: cross-thread reduce arrays
    __shared__ float r2[RB][257];
    __shared__ int   rix[RB][257];
    const int t = threadIdx.x;
    unsigned nf = wsu[W_NFLAG];
    if (nf > FLAGCAP) nf = FLAGCAP;
    unsigned nb = (nf + RB - 1) / RB;
    for (unsigned b = blockIdx.x; b < nb; b += gridDim.x) {
        __syncthreads();
        if (t < RB) {
            unsigned fi = b * RB + t;
            if (fi < nf) {
                sgp[t] = wsu[W_FLAG + 2 * fi];
                sfd[t] = __uint_as_float(wsu[W_FLAG + 2 * fi + 1]);
            } else { sgp[t] = 0u; sfd[t] = 0.0f; }
        }
        __syncthreads();
        // stage 16 z-rows (16 threads per row, 8 floats each)
        {
            int p = t >> 4, j = t & 15;
            const float4* src = (const float4*)(z + (size_t)sgp[p] * DIM);
            *(float4*)&zs[p][j * 8] = src[j * 2];
            *(float4*)&zs[p][j * 8 + 4] = src[j * 2 + 1];
        }
        __syncthreads();
        if (t < RB) {
            float s = 0.0f;
            for (int d = 0; d < DIM; d += 4) {
                float4 v = *(const float4*)&zs[t][d];
                s += v.x * v.x + v.y * v.y + v.z * v.z + v.w * v.w;
            }
            zns[t] = s;
        }
        // dots: clusters c0=2t, c1=2t+1 vs all 16 points
        float acc0[RB], acc1[RB];
#pragma unroll
        for (int p = 0; p < RB; p++) { acc0[p] = 0.0f; acc1[p] = 0.0f; }
        const float4* e0 = (const float4*)(emb + (size_t)(2 * t) * DIM);
        const float4* e1 = (const float4*)(emb + (size_t)(2 * t + 1) * DIM);
#pragma unroll 2
        for (int ch = 0; ch < 32; ch++) {
            float4 ea = e0[ch], eb = e1[ch];
#pragma unroll
            for (int p = 0; p < RB; p++) {
                float4 zv = *(const float4*)&zs[p][ch * 4];   // LDS broadcast
                acc0[p] = fmaf(zv.x, ea.x, fmaf(zv.y, ea.y, fmaf(zv.z, ea.z, fmaf(zv.w, ea.w, acc0[p]))));
                acc1[p] = fmaf(zv.x, eb.x, fmaf(zv.y, eb.y, fmaf(zv.z, eb.z, fmaf(zv.w, eb.w, acc1[p]))));
            }
        }
        float en0 = wsf[W_ENORM + 2 * t];
        float en1 = wsf[W_ENORM + 2 * t + 1];
#pragma unroll
        for (int p = 0; p < RB; p++) {
            float d0 = fmaf(-2.0f, acc0[p], en0);
            float d1 = fmaf(-2.0f, acc1[p], en1);
            float v1 = d0, v2 = d1; int i1 = 2 * t;
            if (d1 < d0) { v1 = d1; i1 = 2 * t + 1; v2 = d0; }
            r1[p][t] = v1; rix[p][t] = i1; r2[p][t] = v2;
        }
        __syncthreads();
        // per-point reduce: 16 threads/point, then in-wave butterfly
        {
            int p = t >> 4, j = t & 15;
            float v1 = 3.4e38f, v2 = 3.4e38f; int i1 = 0x7fffffff;
#pragma unroll
            for (int k = 0; k < 16; k++) {
                int idx = j + 16 * k;
                float c1 = r1[p][idx]; int ci = rix[p][idx]; float c2 = r2[p][idx];
                if (c1 < v1 || (c1 == v1 && ci < i1)) { v2 = fminf(v1, c2); v1 = c1; i1 = ci; }
                else v2 = fminf(v2, c1);
            }
#pragma unroll
            for (int m = 1; m < 16; m <<= 1) {
                float c1 = __shfl_xor(v1, m);
                int ci = __shfl_xor(i1, m);
                float c2 = __shfl_xor(v2, m);
                if (c1 < v1 || (c1 == v1 && ci < i1)) { v2 = fminf(v1, c2); v1 = c1; i1 = ci; }
                else v2 = fminf(v2, c1);
            }
            bool valid = (b * RB + (unsigned)p < nf);
            unsigned gp = sgp[p];
            int chg = 0;
            if (j == 0 && valid) {
                if (v2 - v1 < MARGIN2) {
                    unsigned pos = atomicAdd(&wsu[W_NFLAG2], 1u);
                    if (pos < FLAG2CAP) {
                        wsu[W_FLAG2 + 2 * pos] = gp;
                        wsu[W_FLAG2 + 2 * pos + 1] = __float_as_uint(sfd[p]);
                    }
                } else {
                    float d = v1 + zns[p];
                    atomicAdd(&wsf[W_LOSS], d - sfd[p]);
                    int iold = wsi[W_IDX + gp];
                    if (i1 != iold) {
                        chg = 1;
                        wsi[W_IDX + gp] = i1;
                        out[O_IDX + gp] = (float)i1;
                        atomicAdd(&wsu[W_COUNTS + iold], (unsigned)-1);
                        atomicAdd(&wsu[W_COUNTS + i1], 1u);
                    }
                }
            }
            chg = __shfl(chg, (t & 63) & ~15);
            if (chg) {   // i1, gp identical across the 16-lane group
                int dd = j * 8;
                *(float4*)&out[(size_t)gp * DIM + dd] =
                    *(const float4*)&emb[(size_t)i1 * DIM + dd];
                *(float4*)&out[(size_t)gp * DIM + dd + 4] =
                    *(const float4*)&emb[(size_t)i1 * DIM + dd + 4];
            }
        }
    }
}

// Tier-2: fp64 full-scan for ultra-near ties (expected ~hundreds)
__global__ __launch_bounds__(256) void k_recheck2(
    const float* __restrict__ z, const float* __restrict__ emb,
    float* __restrict__ out, float* __restrict__ wsf,
    unsigned* __restrict__ wsu, int* __restrict__ wsi) {
    __shared__ float zrow[DIM];
    __shared__ double sd[256];
    __shared__ int si[256];
    __shared__ int schg, snew;
    const int t = threadIdx.x;
    unsigned nf = wsu[W_NFLAG2];
    if (nf > FLAG2CAP) nf = FLAG2CAP;
    for (unsigned fi = blockIdx.x; fi < nf; fi += gridDim.x) {
        unsigned gp = wsu[W_FLAG2 + 2 * fi];
        float fd_prov = __uint_as_float(wsu[W_FLAG2 + 2 * fi + 1]);
        __syncthreads();
        if (t < DIM) zrow[t] = z[(size_t)gp * DIM + t];
        __syncthreads();
        double best = 1e300; int bi = 0;
        for (int c = t; c < KCL; c += 256) {
            const float* er = emb + (size_t)c * DIM;
            double d = 0.0;
            for (int dd = 0; dd < DIM; dd++) {
                double df = (double)zrow[dd] - (double)er[dd];
                d += df * df;
            }
            if (d < best) { best = d; bi = c; }
        }
        sd[t] = best; si[t] = bi;
        __syncthreads();
        for (int o = 128; o > 0; o >>= 1) {
            if (t < o) {
                if (sd[t + o] < sd[t] || (sd[t + o] == sd[t] && si[t + o] < si[t])) {
                    sd[t] = sd[t + o]; si[t] = si[t + o];
                }
            }
            __syncthreads();
        }
        if (t == 0) {
            int inew = si[0];
            int iold = wsi[W_IDX + gp];
            snew = inew;
            schg = (inew != iold);
            atomicAdd(&wsf[W_LOSS], (float)sd[0] - fd_prov);
            if (inew != iold) {
                wsi[W_IDX + gp] = inew;
                out[O_IDX + gp] = (float)inew;
                atomicAdd(&wsu[W_COUNTS + iold], (unsigned)-1);
                atomicAdd(&wsu[W_COUNTS + inew], 1u);
            }
        }
        __syncthreads();
        if (schg && t < DIM) out[(size_t)gp * DIM + t] = emb[(size_t)snew * DIM + t];
        __syncthreads();
    }
}

__global__ void k_finalize(const float* __restrict__ ema_cs, float* __restrict__ out,
                           float* __restrict__ wsf, unsigned* __restrict__ wsu) {
    __shared__ float s[KCL];
    __shared__ unsigned sc[KCL];
    int t = threadIdx.x;  // 512 threads
    unsigned c = wsu[W_COUNTS + t];
    float necs = ema_cs[t] * DECAY + (1.0f - DECAY) * (float)c;
    out[O_NECS + t] = necs;
    s[t] = necs;
    __syncthreads();
    for (int o = 256; o > 0; o >>= 1) {
        if (t < o) s[t] += s[t + o];
        __syncthreads();
    }
    float n = s[0];
    float cs = (necs + EPSV) / (n + (float)KCL * EPSV) * n;
    wsf[W_CS + t] = cs;
    sc[t] = c;
    __syncthreads();
    for (int o = 1; o < KCL; o <<= 1) {
        unsigned v = (t >= o) ? sc[t - o] : 0u;
        __syncthreads();
        sc[t] += v;
        __syncthreads();
    }
    unsigned excl = sc[t] - c;
    wsu[W_OFF + t] = excl;
    wsu[W_CUR + t] = excl;
    if (t == 0) {
        out[O_LOSS] = CCOST * wsf[W_LOSS] / (float)((size_t)NPTS * DIM);
        wsu[W_OFF + KCL] = NPTS;
    }
}

__global__ void k_scatter(unsigned* __restrict__ wsu, const int* __restrict__ wsi) {
    int p = blockIdx.x * blockDim.x + threadIdx.x;
    int k = wsi[W_IDX + p];
    unsigned pos = atomicAdd(&wsu[W_CUR + k], 1u);
    wsu[W_SORTED + pos] = (unsigned)p;
}

__global__ __launch_bounds__(256) void k_dwseg(
    const float* __restrict__ z, float* __restrict__ wsf,
    const unsigned* __restrict__ wsu) {
    __shared__ unsigned soff[KCL + 1];
    __shared__ unsigned sidx[SEG];
    const int t = threadIdx.x;
    for (int i = t; i < KCL + 1; i += 256) soff[i] = wsu[W_OFF + i];
    const int base = blockIdx.x * SEG;
    if (t < SEG) sidx[t] = wsu[W_SORTED + base + t];
    __syncthreads();

    const int r = t >> 7;
    const int d = t & 127;
    const int pos0 = base + r;
    int lo = 0, hi = KCL;
    while (lo < hi) {
        int mid = (lo + hi + 1) >> 1;
        if (soff[mid] <= (unsigned)pos0) lo = mid; else hi = mid - 1;
    }
    int curk = lo;
    float acc = 0.0f;
#pragma unroll 4
    for (int j = 0; j < SEG / 2; j++) {
        int pos = pos0 + 2 * j;
        unsigned p = sidx[pos - base];
        while ((unsigned)pos >= soff[curk + 1]) {
            if (acc != 0.0f) atomicAdd(&wsf[W_DW + curk * DIM + d], acc);
            acc = 0.0f;
            curk++;
        }
        acc += z[(size_t)p * DIM + d];
    }
    atomicAdd(&wsf[W_DW + curk * DIM + d], acc);
}

__global__ void k_emb(const float* __restrict__ ema_w, float* __restrict__ out,
                      const float* __restrict__ wsf) {
    int i = blockIdx.x * 256 + threadIdx.x;
    int k = i >> 7;
    float dw = wsf[W_DW + i];
    float nw = ema_w[i] * DECAY + (1.0f - DECAY) * dw;
    out[O_NEMAW + i] = nw;
    out[O_NEMB + i] = nw / wsf[W_CS + k];
}

extern "C" void kernel_launch(void* const* d_in, const int* in_sizes, int n_in,
                              void* d_out, int out_size, void* d_ws, size_t ws_size,
                              hipStream_t stream) {
    const float* z = (const float*)d_in[0];
    const float* emb = (const float*)d_in[1];
    const float* ema_cs = (const float*)d_in[2];
    const float* ema_w = (const float*)d_in[3];
    float* out = (float*)d_out;
    float* wsf = (float*)d_ws;
    unsigned* wsu = (unsigned*)d_ws;
    int* wsi = (int*)d_ws;
    unsigned short* ehi = (unsigned short*)(wsu + W_EHI);

    // zero counts + loss + nflag + nflag2 + dw (contiguous region)
    hipMemsetAsync((char*)d_ws + (size_t)W_COUNTS * 4, 0,
                   (size_t)(W_DW + KCL * DIM - W_COUNTS) * 4, stream);

    k_prep<<<32, 256, 0, stream>>>(emb, ehi, wsf);
    k_main<<<NPTS / 128, 256, 0, stream>>>(z, emb, ehi, out, wsf, wsu, wsi);
    k_recheck1<<<512, 256, 0, stream>>>(z, emb, out, wsf, wsu, wsi);
    k_recheck2<<<256, 256, 0, stream>>>(z, emb, out, wsf, wsu, wsi);
    k_finalize<<<1, KCL, 0, stream>>>(ema_cs, out, wsf, wsu);
    k_scatter<<<NPTS / 256, 256, 0, stream>>>(wsu, wsi);
    k_dwseg<<<NPTS / SEG, 256, 0, stream>>>(z, wsf, wsu);
    k_emb<<<KCL * DIM / 256, 256, 0, stream>>>(ema_w, out, wsf);
}